// Round 2
// baseline (251.509 us; speedup 1.0000x reference)
//
#include <hip/hip_runtime.h>

// Problem: b=1, m=128 variants, n=256 positions, c=22 classes.
// motifs[m,i,c] = ei[i,c] + sum_j eij[i,j,c,v[m,j]] * mask_vec[v[m,j]]
// logits[m,i]  = motifs[m,i,v[m,i]];  vl[m] = sigma * sum_i (logits[m,i]-logits[0,i])*vm
#define NC    22
#define NI    256
#define NJ    256
#define NM    128
#define JG    8              // j's per superstep
#define NSS   (NJ/JG)        // 32 supersteps -> all 256 j in ONE block
#define SLOT  512            // f32 per staged j: 484 data + 28 zero pad (d-overrun reads)
#define DEPTH 4              // LDS ring depth: load(s) issued at iter s-3 (T4 counted vmcnt)
#define MOTLD 23             // padded row stride of LDS motif accumulator

typedef __attribute__((ext_vector_type(8))) short short8;  // bf16x8 MFMA A/B frag
typedef __attribute__((ext_vector_type(4))) float f32x4;   // fp32x4 C/D frag

__device__ __forceinline__ uint32_t bf16rne(float x) {     // fp32 -> bf16 bits (RNE)
    uint32_t u = __float_as_uint(x);
    u += 0x7FFFu + ((u >> 16) & 1u);
    return u >> 16;
}

__device__ __forceinline__ uint32_t pk_bf16(float lo, float hi) {
    uint32_t r;
    asm("v_cvt_pk_bf16_f32 %0, %1, %2" : "=v"(r) : "v"(lo), "v"(hi));
    return r;
}

// Async global->LDS, 16 B/lane. Global addr per-lane; LDS dest wave-uniform
// base + lane*16 (m104/m173 semantics).
__device__ __forceinline__ void gload_lds16(const void* g, void* l) {
    __builtin_amdgcn_global_load_lds(
        (const __attribute__((address_space(1))) void*)g,
        (__attribute__((address_space(3))) void*)l, 16, 0, 0);
}

#define WAITV(n) asm volatile("s_waitcnt vmcnt(" #n ")" ::: "memory")

union u32x4s8 { uint32_t u[4]; short8 s; };

// One block per i (256 blocks, 1024 thr = 16 waves, 1 block/CU).
// Wave w: j-slot jl=w>>1, m-half mh=w&1. Per superstep per wave: exactly ONE
// async 1 KB eij load (uniform vmcnt counting) + 8 MFMA.
// Pipeline (T3/T4): iter s does  WAITV(2) [own load(s) landed] -> s_barrier
// [everyone's load(s) landed; also proves all compute(s-1) retired, so the
// ring slot (s+3)&3 == (s-1)&3 is free] -> issue load(s+3) -> compute(s).
// vmcnt never drains to 0 in the main loop (tail: 2->1->0).
__global__ __launch_bounds__(1024) void potts_fused(
    const int*   __restrict__ variant,   // [128,256] int32
    const float* __restrict__ eij,       // [256,256,22,22]
    const float* __restrict__ ei,        // [256,22]
    const float* __restrict__ mask_vec,  // [22]
    float*       __restrict__ out_motifs,// [128,256,22]
    float*       __restrict__ out_logits)// [128,256]
{
    const int i    = blockIdx.x;
    const int tid  = threadIdx.x;
    const int lane = tid & 63;
    const int w    = tid >> 6;          // wave 0..15
    const int jl   = w >> 1;            // j slot 0..7
    const int mh   = w & 1;             // m half 0..1
    const int q    = lane >> 4;         // k-quad / row-quad
    const int nl   = lane & 15;         // frag row/col
    const int c1   = 16 + nl;
    const int c1r  = (c1 < NC) ? c1 : 0;
    const int kb   = q * 4;

    __shared__ float         tile[DEPTH][JG][SLOT]; // 64 KB eij f32 ring
    __shared__ unsigned char vt8[NJ][NM];           // 32 KB: v[j][m] as u8, staged ONCE
    __shared__ uint32_t      patTab[32];            // bf16(mask_vec[v]) pre-shifted to v&1 half

    // ---- one-time init ----
    if (tid < 32) {
        const uint32_t mb = (tid < NC) ? bf16rne(mask_vec[tid]) : 0u;
        patTab[tid] = mb << ((tid & 1) << 4);
    }
    // zero slot pads (floats 484..511 of every slot in every ring buffer):
    // B-frag row c=21, q=3 reads up to float 493; DMA never writes >=484.
    for (int p = tid; p < DEPTH * JG * (SLOT - 484); p += 1024) {
        const int b = p / (JG * 28), r = p % (JG * 28);
        tile[b][r / 28][484 + (r % 28)] = 0.f;
    }
    // whole variant table -> u8 LDS, layout [j][m] (loop reads are 4-dword
    // broadcast groups -> conflict-free). Coalesced global reads.
    for (int p = tid; p < NM * NJ; p += 1024)
        vt8[p & (NJ - 1)][p >> 8] = (unsigned char)variant[p];
    __syncthreads();   // commits vt8/pads/patTab; no VMEM in flight yet

    // eij staging: slot jl split in halves by mh: floats 0..255 / 228..483
    // (28-float overlap written twice with identical data -> benign).
    const int    poff  = mh ? 228 : 0;
    const size_t ebase = ((size_t)i * NJ + jl) * 484 + poff + lane * 4;

    // prologue: fill ring slots 0..2
    gload_lds16(eij + ebase,                           &tile[0][jl][poff]);
    gload_lds16(eij + ebase + (size_t)1 * (JG * 484),  &tile[1][jl][poff]);
    gload_lds16(eij + ebase + (size_t)2 * (JG * 484),  &tile[2][jl][poff]);

    f32x4 acc[4][2];
    #pragma unroll
    for (int mt = 0; mt < 4; ++mt) {
        acc[mt][0] = (f32x4){0.f, 0.f, 0.f, 0.f};
        acc[mt][1] = (f32x4){0.f, 0.f, 0.f, 0.f};
    }

    for (int s = 0; s < NSS; ++s) {
        // own load(s) landed: outstanding = loads issued after s = min(2, NSS-1-s)
        if      (s <= NSS - 3) WAITV(2);
        else if (s == NSS - 2) WAITV(1);
        else                   WAITV(0);
        __builtin_amdgcn_s_barrier();      // all waves' load(s) landed; compute(s-1) retired
        asm volatile("" ::: "memory");     // fence: keep the ds_reads below the barrier

        if (s + 3 < NSS)                   // refill ring slot (s-1)&3, free per barrier
            gload_lds16(eij + ebase + (size_t)(s + 3) * (JG * 484),
                        &tile[(s + 3) & 3][jl][poff]);

        // ---- compute j = s*8 + jl for m rows mh*64..mh*64+63 ----
        // B-frag lane(q,nl): row c, floats c*22 + q*8..+7 (b64 pairs, ~2-way
        // bank aliasing = free per m136).
        const float* jrow = &tile[s & 3][jl][0];
        const float* r0 = jrow + nl * NC + q * 8;
        const float* r1 = jrow + c1r * NC + q * 8;
        const float2 x0 = *(const float2*)(r0 + 0);
        const float2 x1 = *(const float2*)(r0 + 2);
        const float2 x2 = *(const float2*)(r0 + 4);
        const float2 x3 = *(const float2*)(r0 + 6);
        const float2 y0 = *(const float2*)(r1 + 0);
        const float2 y1 = *(const float2*)(r1 + 2);
        const float2 y2 = *(const float2*)(r1 + 4);
        const float2 y3 = *(const float2*)(r1 + 6);
        u32x4s8 B0, B1;
        B0.u[0] = pk_bf16(x0.x, x0.y);  B0.u[1] = pk_bf16(x1.x, x1.y);
        B0.u[2] = pk_bf16(x2.x, x2.y);  B0.u[3] = pk_bf16(x3.x, x3.y);
        B1.u[0] = pk_bf16(y0.x, y0.y);  B1.u[1] = pk_bf16(y1.x, y1.y);
        B1.u[2] = pk_bf16(y2.x, y2.y);  B1.u[3] = pk_bf16(y3.x, y3.y);

        // A one-hot: A[m][d=v] = bf16(mask_vec[v]) (mask folded into A).
        const unsigned char* vrow = &vt8[s * JG + jl][mh * 64 + nl];
        #pragma unroll
        for (int mt = 0; mt < 4; ++mt) {
            const int      va = vrow[mt * 16];
            const uint32_t pa = patTab[va];
            const int      ha = va >> 1;
            u32x4s8 A;
            #pragma unroll
            for (int t = 0; t < 4; ++t) A.u[t] = (ha == kb + t) ? pa : 0u;
            acc[mt][0] = __builtin_amdgcn_mfma_f32_16x16x32_bf16(A.s, B0.s, acc[mt][0], 0, 0, 0);
            acc[mt][1] = __builtin_amdgcn_mfma_f32_16x16x32_bf16(A.s, B1.s, acc[mt][1], 0, 0, 0);
        }
    }

    // ---- fused epilogue: 8-way jl reduction via LDS f32 atomics ----
    __syncthreads();                         // all compute done (vmcnt already 0); reuse tile
    float* mot = &tile[0][0][0];             // [128][MOTLD] = 11.5 KB
    for (int p = tid; p < NM * MOTLD; p += 1024) mot[p] = 0.f;
    __syncthreads();
    // C/D layout (m89-verified): col = lane&15, row = (lane>>4)*4 + t.
    #pragma unroll
    for (int mt = 0; mt < 4; ++mt) {
        #pragma unroll
        for (int t = 0; t < 4; ++t) {
            const int row = mh * 64 + mt * 16 + q * 4 + t;
            atomicAdd(&mot[row * MOTLD + nl], acc[mt][0][t]);
            if (c1 < NC) atomicAdd(&mot[row * MOTLD + c1], acc[mt][1][t]);
        }
    }
    __syncthreads();
    const float* eirow = ei + i * NC;
    for (int p = tid; p < NM * 32; p += 1024) {
        const int m = p >> 5, c = p & 31;
        if (c < NC)
            out_motifs[((size_t)m * NI + i) * NC + c] = mot[m * MOTLD + c] + eirow[c];
    }
    if (tid < NM) {
        const int vi = vt8[i][tid];          // v[m=tid][j=i]
        out_logits[tid * NI + i] = mot[tid * MOTLD + vi] + eirow[vi];
    }
}

// variant_logit[m] = sigma * sum_i (logits[m,i]-logits[0,i]) * vm[m,i]*vm[0,i]
__global__ __launch_bounds__(64) void potts_pool(
    const float* __restrict__ logits,  // [128,256]
    const float* __restrict__ vmask,   // [128,256]
    const float* __restrict__ sigma,   // [1]
    float*       __restrict__ out_vl)  // [128]
{
    const int m    = blockIdx.x;
    const int lane = threadIdx.x;
    float s = 0.f;
    #pragma unroll
    for (int qq = 0; qq < 4; ++qq) {
        const int i = lane + 64 * qq;
        const float vl = logits[m * NI + i] - logits[i];
        s += vl * vmask[m * NI + i] * vmask[i];
    }
    #pragma unroll
    for (int off = 32; off > 0; off >>= 1)
        s += __shfl_down(s, off, 64);
    if (lane == 0) out_vl[m] = sigma[0] * s;
}

extern "C" void kernel_launch(void* const* d_in, const int* in_sizes, int n_in,
                              void* d_out, int out_size, void* d_ws, size_t ws_size,
                              hipStream_t stream) {
    const int*   variant  = (const int*)  d_in[0];  // [1,128,256] int32
    const float* vmask    = (const float*)d_in[1];  // [1,128,256]
    const float* eij      = (const float*)d_in[2];  // [1,256,256,22,22]
    const float* ei       = (const float*)d_in[3];  // [1,256,22]
    const float* mask_vec = (const float*)d_in[4];  // [22]
    const float* sigma    = (const float*)d_in[5];  // [1]

    float* out        = (float*)d_out;
    float* out_motifs = out;                        // 128*256*22
    float* out_logits = out_motifs + NM * NI * NC;  // 128*256
    float* out_vl     = out_logits + NM * NI;       // 128

    potts_fused<<<NI, 1024, 0, stream>>>(variant, eij, ei, mask_vec,
                                         out_motifs, out_logits);
    potts_pool<<<NM, 64, 0, stream>>>(out_logits, vmask, sigma, out_vl);
}

// Round 3
// 208.806 us; speedup vs baseline: 1.2045x; 1.2045x over previous
//
#include <hip/hip_runtime.h>

// Problem constants: b=1, m=128, n=256 (positions), c=22 classes
#define NC    22
#define NROW  (NC*NC)        // 484 floats per (i,j) coupling block
#define NJ    256
#define NI    256
#define NM    128
#define JG    8              // j's per superstep
#define NQJ   8              // j-eighths (blockIdx.y) -> 2048 blocks, 5/CU (LDS cap)
#define JQ    (NJ/NQJ)       // 32 j's per block
#define SS    (JQ/JG)        // 4 supersteps
#define ROWDW 16             // dwords per (j,c) row: 32 bf16 (d padded 22->32)
#define JROW  (NC*ROWDW)     // 352 dwords per j
#define TILEDW (JG*JROW)     // 2816 dwords per buffer (11264 B)
#define F4PS  (JG*NROW/4)    // 968 float4 staged per superstep
#define SLAB  (NI*NM*NC)     // 720896 floats per j-eighth partial slab

typedef __attribute__((ext_vector_type(8))) short short8;  // bf16x8 A/B frag
typedef __attribute__((ext_vector_type(4))) float f32x4;   // fp32x4 C/D frag

__device__ __forceinline__ uint32_t pk_bf16(float lo, float hi) { // 2xf32 -> packed bf16 (RNE)
    uint32_t r;
    asm("v_cvt_pk_bf16_f32 %0, %1, %2" : "=v"(r) : "v"(lo), "v"(hi));
    return r;
}

// part[jq][i][m][c] = sum_{j in eighth} eij[i,j,c,v[m,j]] * mask_vec[v[m,j]]
// MFMA formulation: hi = A(one-hot over (j,d)) x B(em), K-block = 32 (one j).
// B-frag (lane n=c, quad q holds B[k=q*8+t][n]) reads 8 consecutive d's ==
// native eij order -> ds_read_b128, no transpose. A-frag built in VALU from
// an LDS-staged v-table. 4 blocks/CU in R0; NQJ=8 raises residency to 5/CU
// (30.7 KB LDS/block, 153.6 KB/CU) for more cross-block latency overlap.
__global__ __launch_bounds__(256) void potts_mfma(
    const int*   __restrict__ variant,   // [128,256] int32
    const float* __restrict__ eij,       // [256,256,22,22]
    const float* __restrict__ mask_vec,  // [22]
    float*       __restrict__ part)      // [8,256,128,22] workspace (23 MB)
{
    const int i    = blockIdx.x;
    const int jq   = blockIdx.y;
    const int tid  = threadIdx.x;
    const int lane = tid & 63;
    const int wv   = tid >> 6;           // wave 0..3
    const int q    = lane >> 4;          // k-quad / row-quad
    const int nl   = lane & 15;          // fragment row/col index

    __shared__ uint32_t tile[2][TILEDW]; // bf16 em tiles, 22528 B
    __shared__ int      vtab[2][JG][NM]; // v[m][j] per superstep, 8192 B
    // total 30720 B -> 5 blocks/CU, 20 waves/CU

    // Zero the d-pad (w=11..15 of every (j,c) row) once per buffer; staging
    // never writes there, MFMA reads it as B[k=22..31][*]. A has zeros at
    // d>=22 but junk here could be NaN (NaN*0=NaN) -> must be 0.
    for (int p = tid; p < 2 * JG * NC * 5; p += 256) {
        const int b  = p / (JG * NC * 5), r = p % (JG * NC * 5);
        const int jl = r / (NC * 5),     r2 = r % (NC * 5);
        tile[b][jl * JROW + (r2 / 5) * ROWDW + 11 + r2 % 5] = 0;
    }

    // Staging decomposition: float4 f4 = r*256+tid covers 968 float4 = 8 j of
    // 484 floats. 484/4=121 float4/j (no j straddle); each float4 = two
    // float2s, each within one 22-float c-row (22 even). Mask folded here.
    int   l0[4], l1[4];
    float mk[4][4];
    bool  act[4];
    #pragma unroll
    for (int r = 0; r < 4; ++r) {
        const int f4 = r * 256 + tid;
        act[r] = (f4 < F4PS);
        const int fc = act[r] ? f4 : 0;
        const int jl = fc / 121, r4 = fc % 121;
        const int f2a = 2 * r4, f2b = f2a + 1;
        const int ca = f2a / 11, wa = f2a % 11;
        const int cb = f2b / 11, wb = f2b % 11;
        l0[r] = jl * JROW + ca * ROWDW + wa;
        l1[r] = jl * JROW + cb * ROWDW + wb;
        mk[r][0] = mask_vec[2 * wa];  mk[r][1] = mask_vec[2 * wa + 1];
        mk[r][2] = mask_vec[2 * wb];  mk[r][3] = mask_vec[2 * wb + 1];
    }

    const float4* gsrc = (const float4*)eij + (size_t)(i * NJ + jq * JQ) * 121;

    // Wave-constant fragment addresses. nt=1 covers c=16..31; c>=22 lanes are
    // clamped to row 0 (real data, never NaN); their D columns are discarded.
    const int c1   = 16 + nl;
    const int off0 = nl * ROWDW + q * 4;
    const int off1 = (c1 < NC ? c1 : 0) * ROWDW + q * 4;
    const int m0a  = wv * 16;            // m-tiles: wv and wv+4
    const int m0b  = wv * 16 + 64;

    f32x4 acc_a0 = {0.f,0.f,0.f,0.f}, acc_a1 = {0.f,0.f,0.f,0.f};
    f32x4 acc_b0 = {0.f,0.f,0.f,0.f}, acc_b1 = {0.f,0.f,0.f,0.f};

    // Prefetch superstep 0 (em float4s + variant dwords)
    float4 pf[4];
    int    vr[4];
    #pragma unroll
    for (int r = 0; r < 4; ++r)
        if (act[r]) pf[r] = gsrc[r * 256 + tid];
    #pragma unroll
    for (int r = 0; r < 4; ++r) {
        const int t = r * 256 + tid;     // t<1024: m=t>>3, jj=t&7 (32B chunks)
        vr[r] = variant[(t >> 3) * NJ + jq * JQ + (t & 7)];
    }

    for (int s = 0; s < SS; ++s) {
        const int bsel = s & 1;
        uint32_t* buf = tile[bsel];

        // Stage em tile as bf16 (mask folded, pk-convert) + v-table
        #pragma unroll
        for (int r = 0; r < 4; ++r) {
            if (act[r]) {
                const float4 v = pf[r];
                buf[l0[r]] = pk_bf16(v.x * mk[r][0], v.y * mk[r][1]);
                buf[l1[r]] = pk_bf16(v.z * mk[r][2], v.w * mk[r][3]);
            }
        }
        #pragma unroll
        for (int r = 0; r < 4; ++r) {
            const int t = r * 256 + tid;
            vtab[bsel][t & 7][t >> 3] = vr[r];
        }
        __syncthreads();
        // One barrier per superstep: writes to buffer b at superstep s+1 occur
        // only after this barrier, which in turn requires all reads of buffer
        // b from superstep s-1 to have retired (program order). Proven in R1.

        // Prefetch next superstep
        if (s + 1 < SS) {
            const float4* gn = gsrc + (size_t)(s + 1) * F4PS;
            #pragma unroll
            for (int r = 0; r < 4; ++r)
                if (act[r]) pf[r] = gn[r * 256 + tid];
            #pragma unroll
            for (int r = 0; r < 4; ++r) {
                const int t = r * 256 + tid;
                vr[r] = variant[(t >> 3) * NJ + jq * JQ + (s + 1) * JG + (t & 7)];
            }
        }

        // 8 j's: per wave per j: 2 vtab b32 (broadcast) + 2 B-frag b128
        // (conflict-free: 64 lanes hit 64 distinct aligned 16B chunks) + 4 MFMA
        #pragma unroll
        for (int jl = 0; jl < JG; ++jl) {
            const uint32_t* jrow = buf + jl * JROW;
            const short8 bf0 = *(const short8*)(jrow + off0);
            const short8 bf1 = *(const short8*)(jrow + off1);

            const int va = vtab[bsel][jl][m0a + nl];
            const int vb = vtab[bsel][jl][m0b + nl];

            // A-frag: one-hot at d=v within k-quad q. Element t of this
            // lane is A[m][q*8+t]; pair-packed: dword u holds d=q*8+2u,+2u+1.
            // pat = 1.0bf16 in the (v&1) half; placed iff v>>1 == q*4+u.
            const uint32_t pa = 0x3F80u << ((va & 1) << 4);
            const uint32_t pb = 0x3F80u << ((vb & 1) << 4);
            const int ha = va >> 1, hb = vb >> 1, kb = q * 4;
            union { uint32_t u[4]; short8 s; } fa, fb;
            #pragma unroll
            for (int t = 0; t < 4; ++t) {
                fa.u[t] = (ha == kb + t) ? pa : 0u;
                fb.u[t] = (hb == kb + t) ? pb : 0u;
            }

            acc_a0 = __builtin_amdgcn_mfma_f32_16x16x32_bf16(fa.s, bf0, acc_a0, 0, 0, 0);
            acc_a1 = __builtin_amdgcn_mfma_f32_16x16x32_bf16(fa.s, bf1, acc_a1, 0, 0, 0);
            acc_b0 = __builtin_amdgcn_mfma_f32_16x16x32_bf16(fb.s, bf0, acc_b0, 0, 0, 0);
            acc_b1 = __builtin_amdgcn_mfma_f32_16x16x32_bf16(fb.s, bf1, acc_b1, 0, 0, 0);
        }
    }

    // Epilogue: C/D layout col=lane&15, row=(lane>>4)*4+reg (m89-verified).
    float* pbase = part + ((size_t)jq * NI + i) * NM * NC;
    #pragma unroll
    for (int t = 0; t < 4; ++t) {
        const int ra = m0a + q * 4 + t, rb = m0b + q * 4 + t;
        pbase[ra * NC + nl] = acc_a0[t];
        pbase[rb * NC + nl] = acc_b0[t];
        if (c1 < NC) {
            pbase[ra * NC + c1] = acc_a1[t];
            pbase[rb * NC + c1] = acc_b1[t];
        }
    }
}

// motifs[m,i,c] = ei[i,c] + sum_jq part[jq,i,m,c];  logits[m,i]=motifs[m,i,v[m,i]]
// Flat 1-output-per-thread grid: 704*1024 = 720896 = NI*NM*NC exactly.
// Key property: slab-local offset i*2816 + (m*22+c) == global thread idx, so
// the 8 partial loads are  part[qq*SLAB + idx]  -- perfectly coalesced, all
// independent (max MLP), no loop serialization. Divisions only feed outputs.
__global__ __launch_bounds__(1024) void potts_reduce(
    const float* __restrict__ part,      // [8,256,128,22]
    const int*   __restrict__ variant,   // [128,256]
    const float* __restrict__ ei,        // [256,22]
    float*       __restrict__ out_motifs,// [128,256,22]
    float*       __restrict__ out_logits)// [128,256]
{
    const int idx = blockIdx.x * 1024 + threadIdx.x;   // < 720896, no guard
    float s = 0.f;
    #pragma unroll
    for (int qq = 0; qq < NQJ; ++qq)
        s += part[(size_t)qq * SLAB + idx];

    const int i = idx / (NM * NC);       // magic-mul
    const int r = idx - i * (NM * NC);
    const int m = r / NC;
    const int c = r - m * NC;

    const float v = s + ei[i * NC + c];
    out_motifs[((size_t)m * NI + i) * NC + c] = v;
    if (c == variant[m * NJ + i])        // 22 threads share each variant read
        out_logits[m * NI + i] = v;
}

// variant_logit[m] = sigma * sum_i (logits[m,i]-logits[0,i]) * vm[m,i]*vm[0,i]
__global__ __launch_bounds__(64) void potts_pool(
    const float* __restrict__ logits,  // [128,256]
    const float* __restrict__ vmask,   // [128,256]
    const float* __restrict__ sigma,   // [1]
    float*       __restrict__ out_vl)  // [128]
{
    const int m    = blockIdx.x;
    const int lane = threadIdx.x;
    float s = 0.f;
    #pragma unroll
    for (int qq = 0; qq < 4; ++qq) {
        const int i = lane + 64 * qq;
        const float vl = logits[m * NI + i] - logits[i];
        s += vl * vmask[m * NI + i] * vmask[i];
    }
    #pragma unroll
    for (int off = 32; off > 0; off >>= 1)
        s += __shfl_down(s, off, 64);
    if (lane == 0) out_vl[m] = sigma[0] * s;
}

extern "C" void kernel_launch(void* const* d_in, const int* in_sizes, int n_in,
                              void* d_out, int out_size, void* d_ws, size_t ws_size,
                              hipStream_t stream) {
    const int*   variant  = (const int*)  d_in[0];  // [1,128,256] int32
    const float* vmask    = (const float*)d_in[1];  // [1,128,256]
    const float* eij      = (const float*)d_in[2];  // [1,256,256,22,22]
    const float* ei       = (const float*)d_in[3];  // [1,256,22]
    const float* mask_vec = (const float*)d_in[4];  // [22]
    const float* sigma    = (const float*)d_in[5];  // [1]

    float* out        = (float*)d_out;
    float* out_motifs = out;                        // 128*256*22
    float* out_logits = out_motifs + NM * NI * NC;  // 128*256
    float* out_vl     = out_logits + NM * NI;       // 128

    float* part = (float*)d_ws;                     // 8*256*128*22 fl = 23 MB

    dim3 gridA(NI, NQJ);
    potts_mfma<<<gridA, 256, 0, stream>>>(variant, eij, mask_vec, part);
    potts_reduce<<<SLAB / 1024, 1024, 0, stream>>>(part, variant, ei,
                                                   out_motifs, out_logits);
    potts_pool<<<NM, 64, 0, stream>>>(out_logits, vmask, sigma, out_vl);
}

// Round 4
// 206.376 us; speedup vs baseline: 1.2187x; 1.0118x over previous
//
#include <hip/hip_runtime.h>

// Problem constants: b=1, m=128, n=256 (positions), c=22 classes
#define NC    22
#define NROW  (NC*NC)        // 484 floats per (i,j) coupling block
#define NJ    256
#define NI    256
#define NM    128
#define JG    8              // j's per superstep
#define NQJ   4              // j-quarters (blockIdx.y) -> 1024 blocks = exactly 4/CU
#define JQ    (NJ/NQJ)       // 64 j's per block
#define SS    (JQ/JG)        // 8 supersteps
#define ROWDW 16             // dwords per (j,c) row: 32 bf16 (d padded 22->32)
#define JROW  (NC*ROWDW)     // 352 dwords per j
#define TILEDW (JG*JROW)     // 2816 dwords per buffer (11264 B)
#define F4PS  (JG*NROW/4)    // 968 float4 staged per superstep
#define SLAB  (NI*NM*NC)     // 720896 floats per j-quarter partial slab

typedef __attribute__((ext_vector_type(8))) short short8;  // bf16x8 A/B frag
typedef __attribute__((ext_vector_type(4))) float f32x4;   // fp32x4 C/D frag

__device__ __forceinline__ uint32_t pk_bf16(float lo, float hi) { // 2xf32 -> packed bf16 (RNE)
    uint32_t r;
    asm("v_cvt_pk_bf16_f32 %0, %1, %2" : "=v"(r) : "v"(lo), "v"(hi));
    return r;
}

// part[jq][i][m][c] = sum_{j in quarter} eij[i,j,c,v[m,j]] * mask_vec[v[m,j]]
// MFMA formulation: hi = A(one-hot over (j,d)) x B(em), K-block = 32 (one j).
// B-frag (lane n=c, quad q holds B[k=q*8+t][n]) reads 8 consecutive d's ==
// native eij order -> ds_read_b128, no transpose. A-frag built in VALU from
// an LDS-staged v-table. NQJ=4 proven optimal (R0 53us controllable vs R3
// NQJ=8 61us: doubled part traffic + unamortized per-block overhead).
__global__ __launch_bounds__(256) void potts_mfma(
    const int*   __restrict__ variant,   // [128,256] int32
    const float* __restrict__ eij,       // [256,256,22,22]
    const float* __restrict__ mask_vec,  // [22]
    float*       __restrict__ part)      // [4,256,128,22] workspace (11.5 MB)
{
    const int i    = blockIdx.x;
    const int jq   = blockIdx.y;
    const int tid  = threadIdx.x;
    const int lane = tid & 63;
    const int wv   = tid >> 6;           // wave 0..3
    const int q    = lane >> 4;          // k-quad / row-quad
    const int nl   = lane & 15;          // fragment row/col index

    __shared__ uint32_t tile[2][TILEDW]; // bf16 em tiles, 22528 B
    __shared__ int      vtab[2][JG][NM]; // v[m][j] per superstep, 8192 B
    // total 30720 B -> 4 blocks/CU (123 KB), 16 waves/CU

    // Zero the d-pad (w=11..15 of every (j,c) row) once per buffer; staging
    // never writes there, MFMA reads it as B[k=22..31][*]. A has zeros at
    // d>=22 but junk here could be NaN (NaN*0=NaN) -> must be 0.
    for (int p = tid; p < 2 * JG * NC * 5; p += 256) {
        const int b  = p / (JG * NC * 5), r = p % (JG * NC * 5);
        const int jl = r / (NC * 5),     r2 = r % (NC * 5);
        tile[b][jl * JROW + (r2 / 5) * ROWDW + 11 + r2 % 5] = 0;
    }

    // Staging decomposition: float4 f4 = r*256+tid covers 968 float4 = 8 j of
    // 484 floats. 484/4=121 float4/j (no j straddle); each float4 = two
    // float2s, each within one 22-float c-row (22 even). Mask folded here.
    int   l0[4], l1[4];
    float mk[4][4];
    bool  act[4];
    #pragma unroll
    for (int r = 0; r < 4; ++r) {
        const int f4 = r * 256 + tid;
        act[r] = (f4 < F4PS);
        const int fc = act[r] ? f4 : 0;
        const int jl = fc / 121, r4 = fc % 121;
        const int f2a = 2 * r4, f2b = f2a + 1;
        const int ca = f2a / 11, wa = f2a % 11;
        const int cb = f2b / 11, wb = f2b % 11;
        l0[r] = jl * JROW + ca * ROWDW + wa;
        l1[r] = jl * JROW + cb * ROWDW + wb;
        mk[r][0] = mask_vec[2 * wa];  mk[r][1] = mask_vec[2 * wa + 1];
        mk[r][2] = mask_vec[2 * wb];  mk[r][3] = mask_vec[2 * wb + 1];
    }

    const float4* gsrc = (const float4*)eij + (size_t)(i * NJ + jq * JQ) * 121;

    // Wave-constant fragment addresses. nt=1 covers c=16..31; c>=22 lanes are
    // clamped to row 0 (real data, never NaN); their D columns are discarded.
    const int c1   = 16 + nl;
    const int off0 = nl * ROWDW + q * 4;
    const int off1 = (c1 < NC ? c1 : 0) * ROWDW + q * 4;
    const int m0a  = wv * 16;            // m-tiles: wv and wv+4
    const int m0b  = wv * 16 + 64;

    f32x4 acc_a0 = {0.f,0.f,0.f,0.f}, acc_a1 = {0.f,0.f,0.f,0.f};
    f32x4 acc_b0 = {0.f,0.f,0.f,0.f}, acc_b1 = {0.f,0.f,0.f,0.f};

    // Prefetch superstep 0 (em float4s + variant dwords)
    float4 pf[4];
    int    vr[4];
    #pragma unroll
    for (int r = 0; r < 4; ++r)
        if (act[r]) pf[r] = gsrc[r * 256 + tid];
    #pragma unroll
    for (int r = 0; r < 4; ++r) {
        const int t = r * 256 + tid;     // t<1024: m=t>>3, jj=t&7 (32B chunks)
        vr[r] = variant[(t >> 3) * NJ + jq * JQ + (t & 7)];
    }

    for (int s = 0; s < SS; ++s) {
        const int bsel = s & 1;
        uint32_t* buf = tile[bsel];

        // Stage em tile as bf16 (mask folded, pk-convert) + v-table
        #pragma unroll
        for (int r = 0; r < 4; ++r) {
            if (act[r]) {
                const float4 v = pf[r];
                buf[l0[r]] = pk_bf16(v.x * mk[r][0], v.y * mk[r][1]);
                buf[l1[r]] = pk_bf16(v.z * mk[r][2], v.w * mk[r][3]);
            }
        }
        #pragma unroll
        for (int r = 0; r < 4; ++r) {
            const int t = r * 256 + tid;
            vtab[bsel][t & 7][t >> 3] = vr[r];
        }
        __syncthreads();
        // One barrier per superstep: writes to buffer b at superstep s+1 occur
        // only after this barrier, which in turn requires all reads of buffer
        // b from superstep s-1 to have retired (program order). Proven in R1.

        // Prefetch next superstep
        if (s + 1 < SS) {
            const float4* gn = gsrc + (size_t)(s + 1) * F4PS;
            #pragma unroll
            for (int r = 0; r < 4; ++r)
                if (act[r]) pf[r] = gn[r * 256 + tid];
            #pragma unroll
            for (int r = 0; r < 4; ++r) {
                const int t = r * 256 + tid;
                vr[r] = variant[(t >> 3) * NJ + jq * JQ + (s + 1) * JG + (t & 7)];
            }
        }

        // 8 j's: per wave per j: 2 vtab b32 (broadcast) + 2 B-frag b128
        // (conflict-free: 64 lanes hit 64 distinct aligned 16B chunks) + 4 MFMA
        #pragma unroll
        for (int jl = 0; jl < JG; ++jl) {
            const uint32_t* jrow = buf + jl * JROW;
            const short8 bf0 = *(const short8*)(jrow + off0);
            const short8 bf1 = *(const short8*)(jrow + off1);

            const int va = vtab[bsel][jl][m0a + nl];
            const int vb = vtab[bsel][jl][m0b + nl];

            // A-frag: one-hot at d=v within k-quad q. Element t of this
            // lane is A[m][q*8+t]; pair-packed: dword u holds d=q*8+2u,+2u+1.
            // pat = 1.0bf16 in the (v&1) half; placed iff v>>1 == q*4+u.
            const uint32_t pa = 0x3F80u << ((va & 1) << 4);
            const uint32_t pb = 0x3F80u << ((vb & 1) << 4);
            const int ha = va >> 1, hb = vb >> 1, kb = q * 4;
            union { uint32_t u[4]; short8 s; } fa, fb;
            #pragma unroll
            for (int t = 0; t < 4; ++t) {
                fa.u[t] = (ha == kb + t) ? pa : 0u;
                fb.u[t] = (hb == kb + t) ? pb : 0u;
            }

            acc_a0 = __builtin_amdgcn_mfma_f32_16x16x32_bf16(fa.s, bf0, acc_a0, 0, 0, 0);
            acc_a1 = __builtin_amdgcn_mfma_f32_16x16x32_bf16(fa.s, bf1, acc_a1, 0, 0, 0);
            acc_b0 = __builtin_amdgcn_mfma_f32_16x16x32_bf16(fb.s, bf0, acc_b0, 0, 0, 0);
            acc_b1 = __builtin_amdgcn_mfma_f32_16x16x32_bf16(fb.s, bf1, acc_b1, 0, 0, 0);
        }
    }

    // Epilogue: C/D layout col=lane&15, row=(lane>>4)*4+reg (m89-verified).
    float* pbase = part + ((size_t)jq * NI + i) * NM * NC;
    #pragma unroll
    for (int t = 0; t < 4; ++t) {
        const int ra = m0a + q * 4 + t, rb = m0b + q * 4 + t;
        pbase[ra * NC + nl] = acc_a0[t];
        pbase[rb * NC + nl] = acc_b0[t];
        if (c1 < NC) {
            pbase[ra * NC + c1] = acc_a1[t];
            pbase[rb * NC + c1] = acc_b1[t];
        }
    }
}

// motifs[m,i,c] = ei[i,c] + sum_jq part[jq,i,m,c];  logits[m,i]=motifs[m,i,v[m,i]]
// Flat 1-output-per-thread grid: 704*1024 = 720896 = NI*NM*NC exactly.
// Key property: slab-local offset i*2816 + (m*22+c) == global thread idx, so
// the 4 partial loads are  part[qq*SLAB + idx]  -- perfectly coalesced, all
// independent (max MLP, part is L2/L3-warm from potts_mfma).
__global__ __launch_bounds__(1024) void potts_reduce(
    const float* __restrict__ part,      // [4,256,128,22]
    const int*   __restrict__ variant,   // [128,256]
    const float* __restrict__ ei,        // [256,22]
    float*       __restrict__ out_motifs,// [128,256,22]
    float*       __restrict__ out_logits)// [128,256]
{
    const int idx = blockIdx.x * 1024 + threadIdx.x;   // < 720896, no guard
    float s = 0.f;
    #pragma unroll
    for (int qq = 0; qq < NQJ; ++qq)
        s += part[(size_t)qq * SLAB + idx];

    const int i = idx / (NM * NC);       // magic-mul
    const int r = idx - i * (NM * NC);
    const int m = r / NC;
    const int c = r - m * NC;

    const float v = s + ei[i * NC + c];
    out_motifs[((size_t)m * NI + i) * NC + c] = v;
    if (c == variant[m * NJ + i])        // 22 threads share each variant read
        out_logits[m * NI + i] = v;
}

// variant_logit[m] = sigma * sum_i (logits[m,i]-logits[0,i]) * vm[m,i]*vm[0,i]
__global__ __launch_bounds__(64) void potts_pool(
    const float* __restrict__ logits,  // [128,256]
    const float* __restrict__ vmask,   // [128,256]
    const float* __restrict__ sigma,   // [1]
    float*       __restrict__ out_vl)  // [128]
{
    const int m    = blockIdx.x;
    const int lane = threadIdx.x;
    float s = 0.f;
    #pragma unroll
    for (int qq = 0; qq < 4; ++qq) {
        const int i = lane + 64 * qq;
        const float vl = logits[m * NI + i] - logits[i];
        s += vl * vmask[m * NI + i] * vmask[i];
    }
    #pragma unroll
    for (int off = 32; off > 0; off >>= 1)
        s += __shfl_down(s, off, 64);
    if (lane == 0) out_vl[m] = sigma[0] * s;
}

extern "C" void kernel_launch(void* const* d_in, const int* in_sizes, int n_in,
                              void* d_out, int out_size, void* d_ws, size_t ws_size,
                              hipStream_t stream) {
    const int*   variant  = (const int*)  d_in[0];  // [1,128,256] int32
    const float* vmask    = (const float*)d_in[1];  // [1,128,256]
    const float* eij      = (const float*)d_in[2];  // [1,256,256,22,22]
    const float* ei       = (const float*)d_in[3];  // [1,256,22]
    const float* mask_vec = (const float*)d_in[4];  // [22]
    const float* sigma    = (const float*)d_in[5];  // [1]

    float* out        = (float*)d_out;
    float* out_motifs = out;                        // 128*256*22
    float* out_logits = out_motifs + NM * NI * NC;  // 128*256
    float* out_vl     = out_logits + NM * NI;       // 128

    float* part = (float*)d_ws;                     // 4*256*128*22 fl = 11.5 MB

    dim3 gridA(NI, NQJ);
    potts_mfma<<<gridA, 256, 0, stream>>>(variant, eij, mask_vec, part);
    potts_reduce<<<SLAB / 1024, 1024, 0, stream>>>(part, variant, ei,
                                                   out_motifs, out_logits);
    potts_pool<<<NM, 64, 0, stream>>>(out_logits, vmask, sigma, out_vl);
}